// Round 1
// baseline (323.149 us; speedup 1.0000x reference)
//
#include <hip/hip_runtime.h>
#include <stdint.h>

#define D_    512
#define H_    2
#define HD_   256
#define B_    16
#define S_    1194
#define MTOK  19104          // B_*S_
#define MPAD  19200          // 150*128
#define SPAD  1216           // 19*64
#define NQKV  1536
#define LOG2E 1.44269504088896340736f

typedef unsigned short u16;
typedef __attribute__((ext_vector_type(8))) short bf16x8;   // 8 bf16 = 4 VGPR
typedef __attribute__((ext_vector_type(4))) float f32x4;

__device__ inline u16 f2bf(float x) {
  union { float f; unsigned u; } c; c.f = x;
  unsigned r = c.u + 0x7fffu + ((c.u >> 16) & 1u);  // RNE
  return (u16)(r >> 16);
}

// ---------------------------------------------------------------------------
// Kernel 1: convert X -> bf16 (padded rows zeroed), W_qkv/W_out -> transposed
// bf16 [N][K] so GEMM B-operand reads are row-major contiguous.
// ---------------------------------------------------------------------------
__global__ void convert_kernel(const float* __restrict__ X,
                               const float* __restrict__ Wqkv,
                               const float* __restrict__ Wout,
                               u16* __restrict__ Xb,
                               u16* __restrict__ Wqt,
                               u16* __restrict__ Wot) {
  const int NX  = MPAD * D_;
  const int NW1 = NQKV * D_;
  const int NW2 = D_ * D_;
  int stride = gridDim.x * blockDim.x;
  for (int i = blockIdx.x * blockDim.x + threadIdx.x; i < NX + NW1 + NW2; i += stride) {
    if (i < NX) {
      Xb[i] = (i < MTOK * D_) ? f2bf(X[i]) : (u16)0;
    } else if (i < NX + NW1) {
      int j = i - NX; int n = j >> 9; int k = j & 511;
      Wqt[j] = f2bf(Wqkv[k * NQKV + n]);
    } else {
      int j = i - NX - NW1; int n = j >> 9; int k = j & 511;
      Wot[j] = f2bf(Wout[k * D_ + n]);
    }
  }
}

// ---------------------------------------------------------------------------
// GEMM core: C[128x128] = A[128xK] @ Bt[128xK]^T, K=512, bf16 MFMA 16x16x32.
// LDS is fragment-major: slot s holds one MFMA fragment's 64 lanes x 16B,
// so all ds_read_b128 are lane-contiguous (conflict-free).
// MODE 0: QKV epilogue (scatter Q,K [b,h,s,d]; V transposed [b,h,d,s], bf16)
// MODE 1: f32 out + bias
// ---------------------------------------------------------------------------
template<int MODE>
__global__ __launch_bounds__(256) void gemm_kernel(
    const u16* __restrict__ A, const u16* __restrict__ Bt,
    const float* __restrict__ bias,
    u16* __restrict__ Qb, u16* __restrict__ Kb, u16* __restrict__ Vt,
    float* __restrict__ Cout)
{
  __shared__ u16 ldsA[2 * 8 * 64 * 8];   // [kk][mfrag][lane][8] = 16 KiB
  __shared__ u16 ldsB[2 * 8 * 64 * 8];

  const int t  = threadIdx.x;
  const int l  = t & 63;
  const int w  = t >> 6;
  const int lr = l >> 4, lc = l & 15;
  const int m0 = blockIdx.x * 128;
  const int n0 = blockIdx.y * 128;
  const int wm = (w >> 1) * 64;          // wave's m offset in tile
  const int wn = (w & 1) * 64;           // wave's n offset in tile

  f32x4 acc[4][4] = {};

  for (int kt = 0; kt < 8; ++kt) {       // K = 8 * 64
    const int k0 = kt * 64;
    __syncthreads();
#pragma unroll
    for (int c = 0; c < 4; ++c) {        // stage A and B tiles (reg-staged)
      int s  = c * 256 + t;              // 0..1023
      int kk = s >> 9, mf = (s >> 6) & 7;
      int col = k0 + kk * 32 + lr * 8;
      int rowa = m0 + mf * 16 + lc;
      *(bf16x8*)&ldsA[s * 8] = *(const bf16x8*)&A [rowa * D_ + col];
      int rowb = n0 + mf * 16 + lc;
      *(bf16x8*)&ldsB[s * 8] = *(const bf16x8*)&Bt[rowb * D_ + col];
    }
    __syncthreads();
#pragma unroll
    for (int kk = 0; kk < 2; ++kk) {
      bf16x8 af[4], bfr[4];
#pragma unroll
      for (int m = 0; m < 4; ++m)
        af[m]  = *(bf16x8*)&ldsA[((kk * 8 + (wm >> 4) + m) * 64 + l) * 8];
#pragma unroll
      for (int n = 0; n < 4; ++n)
        bfr[n] = *(bf16x8*)&ldsB[((kk * 8 + (wn >> 4) + n) * 64 + l) * 8];
#pragma unroll
      for (int m = 0; m < 4; ++m)
#pragma unroll
        for (int n = 0; n < 4; ++n)
          acc[m][n] = __builtin_amdgcn_mfma_f32_16x16x32_bf16(af[m], bfr[n], acc[m][n], 0, 0, 0);
    }
  }

  // Epilogue. C frag layout: col = lane&15, row = (lane>>4)*4 + reg  [m89]
#pragma unroll
  for (int n = 0; n < 4; ++n) {
    int j = n0 + wn + n * 16 + lc;
    float bj = bias[j];
    if (MODE == 0) {
      int which = j >> 9, jj = j & 511, h = jj >> 8, d = jj & 255;
#pragma unroll
      for (int m = 0; m < 4; ++m) {
#pragma unroll
        for (int r = 0; r < 4; ++r) {
          int i = m0 + wm + m * 16 + lr * 4 + r;
          if (i < MTOK) {
            int b = i / S_, s = i - b * S_;
            u16 v = f2bf(acc[m][n][r] + bj);
            int bh = b * H_ + h;
            if      (which == 0) Qb[(bh * SPAD + s) * HD_ + d] = v;
            else if (which == 1) Kb[(bh * SPAD + s) * HD_ + d] = v;
            else                 Vt[(bh * HD_ + d) * SPAD + s] = v;  // transposed
          }
        }
      }
    } else {
#pragma unroll
      for (int m = 0; m < 4; ++m)
#pragma unroll
        for (int r = 0; r < 4; ++r) {
          int i = m0 + wm + m * 16 + lr * 4 + r;
          if (i < MTOK) Cout[i * D_ + j] = acc[m][n][r] + bj;
        }
    }
  }
}

// ---------------------------------------------------------------------------
// Kernel 3: causal flash attention. Block = (q-tile of 64) x (b*h).
// 4 waves, each owns 16 q rows. KV tile = 64. Q held in registers.
// K and Vt staged in fragment-major LDS (conflict-free b128 reads).
// Online softmax in f32; P through padded [16][72] LDS per wave.
// ---------------------------------------------------------------------------
__global__ __launch_bounds__(256) void attn_kernel(
    const u16* __restrict__ Qb, const u16* __restrict__ Kb,
    const u16* __restrict__ Vt, u16* __restrict__ Ob)
{
  __shared__ u16 ldsK[32 * 64 * 8];       // 32 KiB, slot = kb*4+nf
  __shared__ u16 ldsV[32 * 64 * 8];       // 32 KiB, slot = kk*16+vf
  __shared__ u16 ldsP[4][16 * 72];        // per-wave P, padded stride 72

  const int qt = blockIdx.x;
  const int bh = blockIdx.y;
  const int q0 = qt * 64;
  const int t  = threadIdx.x, l = t & 63, w = t >> 6;
  const int lr = l >> 4, lc = l & 15;

  // Q fragments in registers: 8 k-blocks of 32 (D=256)
  bf16x8 qf[8];
  const u16* qbase = Qb + (size_t)(bh * SPAD + q0 + w * 16 + lc) * HD_ + lr * 8;
#pragma unroll
  for (int kb = 0; kb < 8; ++kb)
    qf[kb] = *(const bf16x8*)(qbase + kb * 32);

  f32x4 oacc[16] = {};
  float mrow[4] = {-1e30f, -1e30f, -1e30f, -1e30f};
  float lsum[4] = {0.f, 0.f, 0.f, 0.f};

  for (int kt = 0; kt <= qt; ++kt) {
    const int kv0 = kt * 64;
    __syncthreads();
#pragma unroll
    for (int c = 0; c < 8; ++c) {         // stage K (32KB) + Vt (32KB)
      int s  = c * 256 + t;               // 0..2047
      int kb = s >> 8, nf = (s >> 6) & 3;
      const u16* ksrc = Kb + (size_t)(bh * SPAD + kv0 + nf * 16 + lc) * HD_ + kb * 32 + lr * 8;
      *(bf16x8*)&ldsK[s * 8] = *(const bf16x8*)ksrc;
      int kk = s >> 10, vf = (s >> 6) & 15;
      const u16* vsrc = Vt + (size_t)(bh * HD_ + vf * 16 + lc) * SPAD + kv0 + kk * 32 + lr * 8;
      *(bf16x8*)&ldsV[s * 8] = *(const bf16x8*)vsrc;
    }
    __syncthreads();

    // S = Q @ K^T  (A = Q rows q, B-frag from K rows kv)
    f32x4 sacc[4] = {};
#pragma unroll
    for (int kb = 0; kb < 8; ++kb) {
#pragma unroll
      for (int nf = 0; nf < 4; ++nf) {
        bf16x8 kf = *(bf16x8*)&ldsK[((kb * 4 + nf) * 64 + l) * 8];
        sacc[nf] = __builtin_amdgcn_mfma_f32_16x16x32_bf16(qf[kb], kf, sacc[nf], 0, 0, 0);
      }
    }

    // mask + online softmax (scale 1/sqrt(256) = 1/16)
    float sval[4][4];
    float pm[4] = {-1e30f, -1e30f, -1e30f, -1e30f};
#pragma unroll
    for (int nf = 0; nf < 4; ++nf) {
      int col = kv0 + nf * 16 + lc;
#pragma unroll
      for (int r = 0; r < 4; ++r) {
        int row = q0 + w * 16 + lr * 4 + r;
        float v = ((col <= row) && (col < S_)) ? sacc[nf][r] * 0.0625f : -1e30f;
        sval[nf][r] = v;
        pm[r] = fmaxf(pm[r], v);
      }
    }
#pragma unroll
    for (int r = 0; r < 4; ++r) {
      pm[r] = fmaxf(pm[r], __shfl_xor(pm[r], 1));
      pm[r] = fmaxf(pm[r], __shfl_xor(pm[r], 2));
      pm[r] = fmaxf(pm[r], __shfl_xor(pm[r], 4));
      pm[r] = fmaxf(pm[r], __shfl_xor(pm[r], 8));
      float mn = fmaxf(mrow[r], pm[r]);
      float sc = exp2f((mrow[r] - mn) * LOG2E);
      mrow[r] = mn;
      lsum[r] *= sc;
#pragma unroll
      for (int nf = 0; nf < 16; ++nf) oacc[nf][r] *= sc;
    }
#pragma unroll
    for (int nf = 0; nf < 4; ++nf) {
#pragma unroll
      for (int r = 0; r < 4; ++r) {
        float p = exp2f((sval[nf][r] - mrow[r]) * LOG2E);
        lsum[r] += p;                      // per-lane partial row sum
        ldsP[w][(lr * 4 + r) * 72 + nf * 16 + lc] = f2bf(p);
      }
    }
    __syncthreads();

    // O += P @ V  (A = P rows q over kv; B-frag from Vt rows d)
#pragma unroll
    for (int kk = 0; kk < 2; ++kk) {
      bf16x8 pf = *(bf16x8*)&ldsP[w][lc * 72 + kk * 32 + lr * 8];
#pragma unroll
      for (int nf = 0; nf < 16; ++nf) {
        bf16x8 vf = *(bf16x8*)&ldsV[((kk * 16 + nf) * 64 + l) * 8];
        oacc[nf] = __builtin_amdgcn_mfma_f32_16x16x32_bf16(pf, vf, oacc[nf], 0, 0, 0);
      }
    }
  }

  // finalize: reduce per-lane partial sums across the 16-lane row group
  float inv[4];
#pragma unroll
  for (int r = 0; r < 4; ++r) {
    float s = lsum[r];
    s += __shfl_xor(s, 1); s += __shfl_xor(s, 2);
    s += __shfl_xor(s, 4); s += __shfl_xor(s, 8);
    inv[r] = 1.0f / s;
  }
  const int b = bh >> 1, h = bh & 1;
#pragma unroll
  for (int r = 0; r < 4; ++r) {
    int q = q0 + w * 16 + lr * 4 + r;
    if (q < S_) {
      size_t base = (size_t)(b * S_ + q) * D_ + h * HD_ + lc;
#pragma unroll
      for (int nf = 0; nf < 16; ++nf)
        Ob[base + nf * 16] = f2bf(oacc[nf][r] * inv[r]);
    }
  }
}

// ---------------------------------------------------------------------------
extern "C" void kernel_launch(void* const* d_in, const int* in_sizes, int n_in,
                              void* d_out, int out_size, void* d_ws, size_t ws_size,
                              hipStream_t stream) {
  const float* X    = (const float*)d_in[0];
  const float* Wqkv = (const float*)d_in[1];
  const float* bqkv = (const float*)d_in[2];
  const float* Wout = (const float*)d_in[3];
  const float* bout = (const float*)d_in[4];
  float* out = (float*)d_out;

  char* ws = (char*)d_ws;
  u16* Xb  = (u16*)ws;  ws += (size_t)MPAD * D_ * 2;
  u16* Wqt = (u16*)ws;  ws += (size_t)NQKV * D_ * 2;
  u16* Wot = (u16*)ws;  ws += (size_t)D_ * D_ * 2;
  u16* Qb  = (u16*)ws;  ws += (size_t)B_ * H_ * SPAD * HD_ * 2;
  u16* Kb  = (u16*)ws;  ws += (size_t)B_ * H_ * SPAD * HD_ * 2;
  u16* Vt  = (u16*)ws;  ws += (size_t)B_ * H_ * SPAD * HD_ * 2;
  u16* Ob  = (u16*)ws;  ws += (size_t)MPAD * D_ * 2;
  // total ~101 MB

  convert_kernel<<<2048, 256, 0, stream>>>(X, Wqkv, Wout, Xb, Wqt, Wot);
  gemm_kernel<0><<<dim3(150, 12), 256, 0, stream>>>(Xb, Wqt, bqkv, Qb, Kb, Vt, nullptr);
  attn_kernel<<<dim3(19, 32), 256, 0, stream>>>(Qb, Kb, Vt, Ob);
  gemm_kernel<1><<<dim3(150, 4), 256, 0, stream>>>(Ob, Wot, bout, nullptr, nullptr, nullptr, out);
}

// Round 2
// 277.538 us; speedup vs baseline: 1.1643x; 1.1643x over previous
//
#include <hip/hip_runtime.h>
#include <stdint.h>

#define D_    512
#define H_    2
#define HD_   256
#define B_    16
#define S_    1194
#define MTOK  19104          // B_*S_
#define MPAD  19200          // 150*128
#define SPAD  1216           // 19*64
#define NQKV  1536
#define NT_   19             // q-tiles of 64
#define LOG2E 1.44269504088896340736f

typedef unsigned short u16;
typedef __attribute__((ext_vector_type(8))) short bf16x8;   // 8 bf16 = 4 VGPR
typedef __attribute__((ext_vector_type(4))) float f32x4;

__device__ inline u16 f2bf(float x) {
  union { float f; unsigned u; } c; c.f = x;
  unsigned r = c.u + 0x7fffu + ((c.u >> 16) & 1u);  // RNE
  return (u16)(r >> 16);
}

// async global->LDS, 16B per lane. LDS dest must be wave-uniform base
// (HW adds lane*16); global src is per-lane.
__device__ inline void async_copy16(void* lds, const void* g) {
  __builtin_amdgcn_global_load_lds(
      (__attribute__((address_space(1))) void*)(g),
      (__attribute__((address_space(3))) void*)(lds),
      16, 0, 0);
}

// ---------------------------------------------------------------------------
// Kernel 1: convert X -> bf16 (padded rows zeroed), W_qkv/W_out -> transposed
// bf16 [N][K] so GEMM B-operand reads are row-major contiguous.
// ---------------------------------------------------------------------------
__global__ void convert_kernel(const float* __restrict__ X,
                               const float* __restrict__ Wqkv,
                               const float* __restrict__ Wout,
                               u16* __restrict__ Xb,
                               u16* __restrict__ Wqt,
                               u16* __restrict__ Wot) {
  const int NX  = MPAD * D_;
  const int NW1 = NQKV * D_;
  const int NW2 = D_ * D_;
  int stride = gridDim.x * blockDim.x;
  for (int i = blockIdx.x * blockDim.x + threadIdx.x; i < NX + NW1 + NW2; i += stride) {
    if (i < NX) {
      Xb[i] = (i < MTOK * D_) ? f2bf(X[i]) : (u16)0;
    } else if (i < NX + NW1) {
      int j = i - NX; int n = j >> 9; int k = j & 511;
      Wqt[j] = f2bf(Wqkv[k * NQKV + n]);
    } else {
      int j = i - NX - NW1; int n = j >> 9; int k = j & 511;
      Wot[j] = f2bf(Wout[k * D_ + n]);
    }
  }
}

// ---------------------------------------------------------------------------
// GEMM core: C[128x128] = A[128xK] @ Bt[128xK]^T, K=512, bf16 MFMA 16x16x32.
// LDS fragment-major (slot = one MFMA fragment, lane-contiguous 16B) ->
// conflict-free ds_read_b128 AND exact fit for global_load_lds.
// MODE 0: QKV epilogue (scatter Q,K [b,h,s,d]; V transposed [b,h,d,s], bf16)
// MODE 1: f32 out + bias
// ---------------------------------------------------------------------------
template<int MODE>
__global__ __launch_bounds__(256) void gemm_kernel(
    const u16* __restrict__ A, const u16* __restrict__ Bt,
    const float* __restrict__ bias,
    u16* __restrict__ Qb, u16* __restrict__ Kb, u16* __restrict__ Vt,
    float* __restrict__ Cout)
{
  __shared__ u16 ldsA[2 * 8 * 64 * 8];   // [kk][mfrag][lane][8] = 16 KiB
  __shared__ u16 ldsB[2 * 8 * 64 * 8];

  const int t  = threadIdx.x;
  const int l  = t & 63;
  const int w  = t >> 6;
  const int lr = l >> 4, lc = l & 15;
  const int m0 = blockIdx.x * 128;
  const int n0 = blockIdx.y * 128;
  const int wm = (w >> 1) * 64;          // wave's m offset in tile
  const int wn = (w & 1) * 64;           // wave's n offset in tile

  f32x4 acc[4][4] = {};

  for (int kt = 0; kt < 8; ++kt) {       // K = 8 * 64
    const int k0 = kt * 64;
    __syncthreads();
#pragma unroll
    for (int c = 0; c < 4; ++c) {        // async stage A and B tiles
      const int base = c * 256 + w * 64;            // slot base (wave-uniform)
      const int kk = (4 * c + w) >> 3;              // uniform per wave
      const int mf = (4 * c + w) & 7;
      const int col = k0 + kk * 32 + lr * 8;
      async_copy16(&ldsA[base * 8], &A [(size_t)(m0 + mf * 16 + lc) * D_ + col]);
      async_copy16(&ldsB[base * 8], &Bt[(size_t)(n0 + mf * 16 + lc) * D_ + col]);
    }
    __syncthreads();
#pragma unroll
    for (int kk = 0; kk < 2; ++kk) {
      bf16x8 af[4], bfr[4];
#pragma unroll
      for (int m = 0; m < 4; ++m)
        af[m]  = *(bf16x8*)&ldsA[((kk * 8 + (wm >> 4) + m) * 64 + l) * 8];
#pragma unroll
      for (int n = 0; n < 4; ++n)
        bfr[n] = *(bf16x8*)&ldsB[((kk * 8 + (wn >> 4) + n) * 64 + l) * 8];
#pragma unroll
      for (int m = 0; m < 4; ++m)
#pragma unroll
        for (int n = 0; n < 4; ++n)
          acc[m][n] = __builtin_amdgcn_mfma_f32_16x16x32_bf16(af[m], bfr[n], acc[m][n], 0, 0, 0);
    }
  }

  // Epilogue. C frag layout: col = lane&15, row = (lane>>4)*4 + reg  [m89]
#pragma unroll
  for (int n = 0; n < 4; ++n) {
    int j = n0 + wn + n * 16 + lc;
    float bj = bias[j];
    if (MODE == 0) {
      int which = j >> 9, jj = j & 511, h = jj >> 8, d = jj & 255;
#pragma unroll
      for (int m = 0; m < 4; ++m) {
#pragma unroll
        for (int r = 0; r < 4; ++r) {
          int i = m0 + wm + m * 16 + lr * 4 + r;
          if (i < MTOK) {
            int b = i / S_, s = i - b * S_;
            u16 v = f2bf(acc[m][n][r] + bj);
            int bh = b * H_ + h;
            if      (which == 0) Qb[(bh * SPAD + s) * HD_ + d] = v;
            else if (which == 1) Kb[(bh * SPAD + s) * HD_ + d] = v;
            else                 Vt[(bh * HD_ + d) * SPAD + s] = v;  // transposed
          }
        }
      }
    } else {
#pragma unroll
      for (int m = 0; m < 4; ++m)
#pragma unroll
        for (int r = 0; r < 4; ++r) {
          int i = m0 + wm + m * 16 + lr * 4 + r;
          if (i < MTOK) Cout[i * D_ + j] = acc[m][n][r] + bj;
        }
    }
  }
}

// ---------------------------------------------------------------------------
// Kernel 3: causal flash attention. 1-D grid of 608 blocks, XCD-swizzled so
// all 19 q-tile blocks of one bh land on one XCD (K/V stay L2-resident);
// qt reversed so longest blocks dispatch first.
// 4 waves x 16 q rows, KV tile 64, Q in registers, K/V async-staged into
// fragment-major LDS, online softmax in f32, P via wave-private padded LDS.
// ---------------------------------------------------------------------------
__global__ __launch_bounds__(256) void attn_kernel(
    const u16* __restrict__ Qb, const u16* __restrict__ Kb,
    const u16* __restrict__ Vt, u16* __restrict__ Ob)
{
  __shared__ u16 ldsK[32 * 64 * 8];       // 32 KiB, slot = kb*4+nf
  __shared__ u16 ldsV[32 * 64 * 8];       // 32 KiB, slot = kk*16+vf
  __shared__ u16 ldsP[4][16 * 72];        // per-wave P, padded stride 72

  // XCD swizzle: block i -> XCD i%8 (HW round-robin). Pin bh%8 == xcd.
  const int id   = blockIdx.x;            // 0..607
  const int xcd  = id & 7;
  const int slot = id >> 3;               // 0..75
  const int bh   = xcd + 8 * (slot / NT_);
  const int qt   = (NT_ - 1) - (slot % NT_);   // long blocks first
  const int q0 = qt * 64;
  const int t  = threadIdx.x, l = t & 63, w = t >> 6;
  const int lr = l >> 4, lc = l & 15;

  // Q fragments in registers: 8 k-blocks of 32 (D=256)
  bf16x8 qf[8];
  const u16* qbase = Qb + (size_t)(bh * SPAD + q0 + w * 16 + lc) * HD_ + lr * 8;
#pragma unroll
  for (int kb = 0; kb < 8; ++kb)
    qf[kb] = *(const bf16x8*)(qbase + kb * 32);

  f32x4 oacc[16] = {};
  float mrow[4] = {-1e30f, -1e30f, -1e30f, -1e30f};
  float lsum[4] = {0.f, 0.f, 0.f, 0.f};

  for (int kt = 0; kt <= qt; ++kt) {
    const int kv0 = kt * 64;
    __syncthreads();
#pragma unroll
    for (int c = 0; c < 8; ++c) {         // async stage K (32KB) + Vt (32KB)
      const int base = c * 256 + w * 64;  // slot base (wave-uniform)
      const int nf = w;                   // K slot = kb*4+nf, kb=c
      const u16* ksrc = Kb + (size_t)(bh * SPAD + kv0 + nf * 16 + lc) * HD_ + c * 32 + lr * 8;
      async_copy16(&ldsK[base * 8], ksrc);
      const int kk = (4 * c + w) >> 4, vf = (4 * c + w) & 15;
      const u16* vsrc = Vt + (size_t)(bh * HD_ + vf * 16 + lc) * SPAD + kv0 + kk * 32 + lr * 8;
      async_copy16(&ldsV[base * 8], vsrc);
    }
    __syncthreads();

    // S = Q @ K^T  (A = Q rows q, B-frag from K rows kv)
    f32x4 sacc[4] = {};
#pragma unroll
    for (int kb = 0; kb < 8; ++kb) {
#pragma unroll
      for (int nf = 0; nf < 4; ++nf) {
        bf16x8 kf = *(bf16x8*)&ldsK[((kb * 4 + nf) * 64 + l) * 8];
        sacc[nf] = __builtin_amdgcn_mfma_f32_16x16x32_bf16(qf[kb], kf, sacc[nf], 0, 0, 0);
      }
    }

    // mask + online softmax (scale 1/sqrt(256) = 1/16)
    float sval[4][4];
    float pm[4] = {-1e30f, -1e30f, -1e30f, -1e30f};
#pragma unroll
    for (int nf = 0; nf < 4; ++nf) {
      int col = kv0 + nf * 16 + lc;
#pragma unroll
      for (int r = 0; r < 4; ++r) {
        int row = q0 + w * 16 + lr * 4 + r;
        float v = ((col <= row) && (col < S_)) ? sacc[nf][r] * 0.0625f : -1e30f;
        sval[nf][r] = v;
        pm[r] = fmaxf(pm[r], v);
      }
    }
#pragma unroll
    for (int r = 0; r < 4; ++r) {
      pm[r] = fmaxf(pm[r], __shfl_xor(pm[r], 1));
      pm[r] = fmaxf(pm[r], __shfl_xor(pm[r], 2));
      pm[r] = fmaxf(pm[r], __shfl_xor(pm[r], 4));
      pm[r] = fmaxf(pm[r], __shfl_xor(pm[r], 8));
      float mn = fmaxf(mrow[r], pm[r]);
      float sc = exp2f((mrow[r] - mn) * LOG2E);
      mrow[r] = mn;
      lsum[r] *= sc;
#pragma unroll
      for (int nf = 0; nf < 16; ++nf) oacc[nf][r] *= sc;
    }
#pragma unroll
    for (int nf = 0; nf < 4; ++nf) {
#pragma unroll
      for (int r = 0; r < 4; ++r) {
        float p = exp2f((sval[nf][r] - mrow[r]) * LOG2E);
        lsum[r] += p;                      // per-lane partial row sum
        ldsP[w][(lr * 4 + r) * 72 + nf * 16 + lc] = f2bf(p);
      }
    }
    // NOTE: no barrier here — P is wave-private; same-wave ds_write->ds_read
    // is ordered by lgkmcnt. ldsV was staged before the post-stage barrier.

    // O += P @ V  (A = P rows q over kv; B-frag from Vt rows d)
#pragma unroll
    for (int kk = 0; kk < 2; ++kk) {
      bf16x8 pf = *(bf16x8*)&ldsP[w][lc * 72 + kk * 32 + lr * 8];
#pragma unroll
      for (int nf = 0; nf < 16; ++nf) {
        bf16x8 vf = *(bf16x8*)&ldsV[((kk * 16 + nf) * 64 + l) * 8];
        oacc[nf] = __builtin_amdgcn_mfma_f32_16x16x32_bf16(pf, vf, oacc[nf], 0, 0, 0);
      }
    }
  }

  // finalize: reduce per-lane partial sums across the 16-lane row group
  float inv[4];
#pragma unroll
  for (int r = 0; r < 4; ++r) {
    float s = lsum[r];
    s += __shfl_xor(s, 1); s += __shfl_xor(s, 2);
    s += __shfl_xor(s, 4); s += __shfl_xor(s, 8);
    inv[r] = 1.0f / s;
  }
  const int b = bh >> 1, h = bh & 1;
#pragma unroll
  for (int r = 0; r < 4; ++r) {
    int q = q0 + w * 16 + lr * 4 + r;
    if (q < S_) {
      size_t base = (size_t)(b * S_ + q) * D_ + h * HD_ + lc;
#pragma unroll
      for (int nf = 0; nf < 16; ++nf)
        Ob[base + nf * 16] = f2bf(oacc[nf][r] * inv[r]);
    }
  }
}

// ---------------------------------------------------------------------------
extern "C" void kernel_launch(void* const* d_in, const int* in_sizes, int n_in,
                              void* d_out, int out_size, void* d_ws, size_t ws_size,
                              hipStream_t stream) {
  const float* X    = (const float*)d_in[0];
  const float* Wqkv = (const float*)d_in[1];
  const float* bqkv = (const float*)d_in[2];
  const float* Wout = (const float*)d_in[3];
  const float* bout = (const float*)d_in[4];
  float* out = (float*)d_out;

  char* ws = (char*)d_ws;
  u16* Xb  = (u16*)ws;  ws += (size_t)MPAD * D_ * 2;
  u16* Wqt = (u16*)ws;  ws += (size_t)NQKV * D_ * 2;
  u16* Wot = (u16*)ws;  ws += (size_t)D_ * D_ * 2;
  u16* Qb  = (u16*)ws;  ws += (size_t)B_ * H_ * SPAD * HD_ * 2;
  u16* Kb  = (u16*)ws;  ws += (size_t)B_ * H_ * SPAD * HD_ * 2;
  u16* Vt  = (u16*)ws;  ws += (size_t)B_ * H_ * SPAD * HD_ * 2;
  u16* Ob  = (u16*)ws;  ws += (size_t)MPAD * D_ * 2;
  // total ~101 MB

  convert_kernel<<<2048, 256, 0, stream>>>(X, Wqkv, Wout, Xb, Wqt, Wot);
  gemm_kernel<0><<<dim3(150, 12), 256, 0, stream>>>(Xb, Wqt, bqkv, Qb, Kb, Vt, nullptr);
  attn_kernel<<<608, 256, 0, stream>>>(Qb, Kb, Vt, Ob);
  gemm_kernel<1><<<dim3(150, 4), 256, 0, stream>>>(Ob, Wot, bout, nullptr, nullptr, nullptr, out);
}

// Round 3
// 269.978 us; speedup vs baseline: 1.1969x; 1.0280x over previous
//
#include <hip/hip_runtime.h>
#include <stdint.h>

#define D_    512
#define H_    2
#define HD_   256
#define B_    16
#define S_    1194
#define MTOK  19104          // B_*S_
#define MPAD  19200          // 75*256
#define SPAD  1216           // 19*64
#define NQKV  1536
#define NT_   19             // q-tiles of 64
#define LOG2E 1.44269504088896340736f

typedef unsigned short u16;
typedef __attribute__((ext_vector_type(8))) short bf16x8;   // 8 bf16 = 4 VGPR
typedef __attribute__((ext_vector_type(4))) float f32x4;

__device__ inline u16 f2bf(float x) {
  union { float f; unsigned u; } c; c.f = x;
  unsigned r = c.u + 0x7fffu + ((c.u >> 16) & 1u);  // RNE
  return (u16)(r >> 16);
}

// async global->LDS, 16B per lane. LDS dest must be wave-uniform base
// (HW adds lane*16); global src is per-lane.
__device__ inline void async_copy16(void* lds, const void* g) {
  __builtin_amdgcn_global_load_lds(
      (__attribute__((address_space(1))) void*)(g),
      (__attribute__((address_space(3))) void*)(lds),
      16, 0, 0);
}

// ---------------------------------------------------------------------------
// Kernel 1: convert X -> bf16 (vectorized, padded rows zeroed), W_qkv/W_out ->
// transposed bf16 [N][K].
// ---------------------------------------------------------------------------
__global__ void convert_kernel(const float* __restrict__ X,
                               const float* __restrict__ Wqkv,
                               const float* __restrict__ Wout,
                               u16* __restrict__ Xb,
                               u16* __restrict__ Wqt,
                               u16* __restrict__ Wot) {
  const int NX8 = MPAD * D_ / 8;       // X handled 8 elems/item
  const int NW1 = NQKV * D_;
  const int NW2 = D_ * D_;
  const int TOT = NX8 + NW1 + NW2;
  int stride = gridDim.x * blockDim.x;
  for (int i = blockIdx.x * blockDim.x + threadIdx.x; i < TOT; i += stride) {
    if (i < NX8) {
      int base = i * 8;
      bf16x8 o;
      if (base < MTOK * D_) {
        f32x4 v0 = *(const f32x4*)&X[base];
        f32x4 v1 = *(const f32x4*)&X[base + 4];
#pragma unroll
        for (int j = 0; j < 4; ++j) { o[j] = (short)f2bf(v0[j]); o[4 + j] = (short)f2bf(v1[j]); }
      } else {
#pragma unroll
        for (int j = 0; j < 8; ++j) o[j] = 0;
      }
      *(bf16x8*)&Xb[base] = o;
    } else if (i < NX8 + NW1) {
      int j = i - NX8; int n = j >> 9; int k = j & 511;
      Wqt[j] = f2bf(Wqkv[k * NQKV + n]);
    } else {
      int j = i - NX8 - NW1; int n = j >> 9; int k = j & 511;
      Wot[j] = f2bf(Wout[k * D_ + n]);
    }
  }
}

// ---------------------------------------------------------------------------
// Pipelined GEMM: C[256 x NBF*64] = A[256xK] @ Bt[NBF*64 x K]^T, K=512,
// bf16 MFMA 16x16x32, 8 waves (512 thr), double-buffered LDS, fragment-major
// layout (conflict-free + global_load_lds-direct).
// Schedule per K-tile (T3 minimum): issue next tile's stages FIRST, then
// ds_read + MFMA (setprio-wrapped), then one __syncthreads (vmcnt+lgkm drain).
// MODE 0: QKV epilogue (scatter Q,K [b,h,s,d]; V transposed [b,h,d,s], bf16)
// MODE 1: f32 out + bias
// ---------------------------------------------------------------------------
template<int MODE, int NBF>      // NBF = B-frags per wave; BN = NBF*64
__global__ __launch_bounds__(512, 2) void gemm_kernel(
    const u16* __restrict__ A, const u16* __restrict__ Bt,
    const float* __restrict__ bias, int nb_grid,
    u16* __restrict__ Qb, u16* __restrict__ Kb, u16* __restrict__ Vt,
    float* __restrict__ Cout)
{
  // A: 32 frags (2kk x 16mf) x 1KB; B: 2kk x NBF*4 nf frags x 1KB; x2 buffers
  __shared__ u16 ldsA[2][32 * 512];
  __shared__ u16 ldsB[2][NBF * 8 * 512];

  const int t  = threadIdx.x;
  const int l  = t & 63;
  const int w  = t >> 6;               // 0..7
  const int lr = l >> 4, lc = l & 15;

  // bijective XCD-chunked swizzle (m204): consecutive wgid -> same XCD chunk
  const int nwg = gridDim.x;
  const int q = nwg >> 3, r = nwg & 7;
  const int xcd = blockIdx.x & 7, off = blockIdx.x >> 3;
  const int wgid = (xcd < r ? xcd * (q + 1) : r * (q + 1) + (xcd - r) * q) + off;
  const int m0 = (wgid / nb_grid) * 256;
  const int n0 = (wgid % nb_grid) * (NBF * 64);

  // per-lane global stage pointers (advance 64 cols per K-tile)
  const u16* pA[4]; const u16* pB[NBF];
#pragma unroll
  for (int c = 0; c < 4; ++c) {
    int f = c * 8 + w, kk = f >> 4, mf = f & 15;
    pA[c] = &A[(size_t)(m0 + mf * 16 + lc) * D_ + kk * 32 + lr * 8];
  }
#pragma unroll
  for (int c = 0; c < NBF; ++c) {
    int f = c * 8 + w, kk = f / (NBF * 4), nf = f % (NBF * 4);
    pB[c] = &Bt[(size_t)(n0 + nf * 16 + lc) * D_ + kk * 32 + lr * 8];
  }

  f32x4 acc[8][NBF] = {};

  // prologue: stage K-tile 0 into buf 0
#pragma unroll
  for (int c = 0; c < 4; ++c) { async_copy16(&ldsA[0][(c * 8 + w) * 512], pA[c]); pA[c] += 64; }
#pragma unroll
  for (int c = 0; c < NBF; ++c) { async_copy16(&ldsB[0][(c * 8 + w) * 512], pB[c]); pB[c] += 64; }
  __syncthreads();

  for (int kt = 0; kt < 8; ++kt) {     // K = 8 * 64
    const int cur = kt & 1, nxt = cur ^ 1;
    if (kt < 7) {                      // issue next tile's stages FIRST
#pragma unroll
      for (int c = 0; c < 4; ++c) { async_copy16(&ldsA[nxt][(c * 8 + w) * 512], pA[c]); pA[c] += 64; }
#pragma unroll
      for (int c = 0; c < NBF; ++c) { async_copy16(&ldsB[nxt][(c * 8 + w) * 512], pB[c]); pB[c] += 64; }
    }
#pragma unroll
    for (int kk = 0; kk < 2; ++kk) {
      bf16x8 af[8], bfr[NBF];
#pragma unroll
      for (int m = 0; m < 8; ++m)
        af[m] = *(bf16x8*)&ldsA[cur][((kk * 16 + (w >> 2) * 8 + m) * 64 + l) * 8];
#pragma unroll
      for (int n = 0; n < NBF; ++n)
        bfr[n] = *(bf16x8*)&ldsB[cur][((kk * NBF * 4 + (w & 3) * NBF + n) * 64 + l) * 8];
      __builtin_amdgcn_s_setprio(1);
#pragma unroll
      for (int m = 0; m < 8; ++m)
#pragma unroll
        for (int n = 0; n < NBF; ++n)
          acc[m][n] = __builtin_amdgcn_mfma_f32_16x16x32_bf16(af[m], bfr[n], acc[m][n], 0, 0, 0);
      __builtin_amdgcn_s_setprio(0);
    }
    __syncthreads();                   // drains vmcnt (next tile landed) + lgkm
  }

  // Epilogue. C frag layout: col = lane&15, row = (lane>>4)*4 + reg  [m89]
#pragma unroll
  for (int n = 0; n < NBF; ++n) {
    int j = n0 + (w & 3) * (NBF * 16) + n * 16 + lc;
    float bj = bias[j];
    if (MODE == 0) {
      int which = j >> 9, jj = j & 511, h = jj >> 8, d = jj & 255;
#pragma unroll
      for (int m = 0; m < 8; ++m) {
#pragma unroll
        for (int rr = 0; rr < 4; ++rr) {
          int i = m0 + (w >> 2) * 128 + m * 16 + lr * 4 + rr;
          if (i < MTOK) {
            int b = i / S_, s = i - b * S_;
            u16 v = f2bf(acc[m][n][rr] + bj);
            int bh = b * H_ + h;
            if      (which == 0) Qb[(bh * SPAD + s) * HD_ + d] = v;
            else if (which == 1) Kb[(bh * SPAD + s) * HD_ + d] = v;
            else                 Vt[(bh * HD_ + d) * SPAD + s] = v;  // transposed
          }
        }
      }
    } else {
#pragma unroll
      for (int m = 0; m < 8; ++m)
#pragma unroll
        for (int rr = 0; rr < 4; ++rr) {
          int i = m0 + (w >> 2) * 128 + m * 16 + lr * 4 + rr;
          if (i < MTOK) Cout[(size_t)i * D_ + j] = acc[m][n][rr] + bj;
        }
    }
  }
}

// ---------------------------------------------------------------------------
// Kernel 3: causal flash attention (unchanged from round 2).
// ---------------------------------------------------------------------------
__global__ __launch_bounds__(256) void attn_kernel(
    const u16* __restrict__ Qb, const u16* __restrict__ Kb,
    const u16* __restrict__ Vt, u16* __restrict__ Ob)
{
  __shared__ u16 ldsK[32 * 64 * 8];       // 32 KiB, slot = kb*4+nf
  __shared__ u16 ldsV[32 * 64 * 8];       // 32 KiB, slot = kk*16+vf
  __shared__ u16 ldsP[4][16 * 72];        // per-wave P, padded stride 72

  const int id   = blockIdx.x;            // 0..607
  const int xcd  = id & 7;
  const int slot = id >> 3;               // 0..75
  const int bh   = xcd + 8 * (slot / NT_);
  const int qt   = (NT_ - 1) - (slot % NT_);   // long blocks first
  const int q0 = qt * 64;
  const int t  = threadIdx.x, l = t & 63, w = t >> 6;
  const int lr = l >> 4, lc = l & 15;

  bf16x8 qf[8];
  const u16* qbase = Qb + (size_t)(bh * SPAD + q0 + w * 16 + lc) * HD_ + lr * 8;
#pragma unroll
  for (int kb = 0; kb < 8; ++kb)
    qf[kb] = *(const bf16x8*)(qbase + kb * 32);

  f32x4 oacc[16] = {};
  float mrow[4] = {-1e30f, -1e30f, -1e30f, -1e30f};
  float lsum[4] = {0.f, 0.f, 0.f, 0.f};

  for (int kt = 0; kt <= qt; ++kt) {
    const int kv0 = kt * 64;
    __syncthreads();
#pragma unroll
    for (int c = 0; c < 8; ++c) {         // async stage K (32KB) + Vt (32KB)
      const int base = c * 256 + w * 64;
      const int nf = w;
      const u16* ksrc = Kb + (size_t)(bh * SPAD + kv0 + nf * 16 + lc) * HD_ + c * 32 + lr * 8;
      async_copy16(&ldsK[base * 8], ksrc);
      const int kk = (4 * c + w) >> 4, vf = (4 * c + w) & 15;
      const u16* vsrc = Vt + (size_t)(bh * HD_ + vf * 16 + lc) * SPAD + kv0 + kk * 32 + lr * 8;
      async_copy16(&ldsV[base * 8], vsrc);
    }
    __syncthreads();

    f32x4 sacc[4] = {};
#pragma unroll
    for (int kb = 0; kb < 8; ++kb) {
#pragma unroll
      for (int nf = 0; nf < 4; ++nf) {
        bf16x8 kf = *(bf16x8*)&ldsK[((kb * 4 + nf) * 64 + l) * 8];
        sacc[nf] = __builtin_amdgcn_mfma_f32_16x16x32_bf16(qf[kb], kf, sacc[nf], 0, 0, 0);
      }
    }

    float sval[4][4];
    float pm[4] = {-1e30f, -1e30f, -1e30f, -1e30f};
#pragma unroll
    for (int nf = 0; nf < 4; ++nf) {
      int col = kv0 + nf * 16 + lc;
#pragma unroll
      for (int r = 0; r < 4; ++r) {
        int row = q0 + w * 16 + lr * 4 + r;
        float v = ((col <= row) && (col < S_)) ? sacc[nf][r] * 0.0625f : -1e30f;
        sval[nf][r] = v;
        pm[r] = fmaxf(pm[r], v);
      }
    }
#pragma unroll
    for (int r = 0; r < 4; ++r) {
      pm[r] = fmaxf(pm[r], __shfl_xor(pm[r], 1));
      pm[r] = fmaxf(pm[r], __shfl_xor(pm[r], 2));
      pm[r] = fmaxf(pm[r], __shfl_xor(pm[r], 4));
      pm[r] = fmaxf(pm[r], __shfl_xor(pm[r], 8));
      float mn = fmaxf(mrow[r], pm[r]);
      float sc = exp2f((mrow[r] - mn) * LOG2E);
      mrow[r] = mn;
      lsum[r] *= sc;
#pragma unroll
      for (int nf = 0; nf < 16; ++nf) oacc[nf][r] *= sc;
    }
#pragma unroll
    for (int nf = 0; nf < 4; ++nf) {
#pragma unroll
      for (int r = 0; r < 4; ++r) {
        float p = exp2f((sval[nf][r] - mrow[r]) * LOG2E);
        lsum[r] += p;
        ldsP[w][(lr * 4 + r) * 72 + nf * 16 + lc] = f2bf(p);
      }
    }
    // no barrier: P is wave-private (same-wave lgkm ordering)

#pragma unroll
    for (int kk = 0; kk < 2; ++kk) {
      bf16x8 pf = *(bf16x8*)&ldsP[w][lc * 72 + kk * 32 + lr * 8];
#pragma unroll
      for (int nf = 0; nf < 16; ++nf) {
        bf16x8 vf = *(bf16x8*)&ldsV[((kk * 16 + nf) * 64 + l) * 8];
        oacc[nf] = __builtin_amdgcn_mfma_f32_16x16x32_bf16(pf, vf, oacc[nf], 0, 0, 0);
      }
    }
  }

  float inv[4];
#pragma unroll
  for (int r = 0; r < 4; ++r) {
    float s = lsum[r];
    s += __shfl_xor(s, 1); s += __shfl_xor(s, 2);
    s += __shfl_xor(s, 4); s += __shfl_xor(s, 8);
    inv[r] = 1.0f / s;
  }
  const int b = bh >> 1, h = bh & 1;
#pragma unroll
  for (int r = 0; r < 4; ++r) {
    int q = q0 + w * 16 + lr * 4 + r;
    if (q < S_) {
      size_t base = (size_t)(b * S_ + q) * D_ + h * HD_ + lc;
#pragma unroll
      for (int nf = 0; nf < 16; ++nf)
        Ob[base + nf * 16] = f2bf(oacc[nf][r] * inv[r]);
    }
  }
}

// ---------------------------------------------------------------------------
extern "C" void kernel_launch(void* const* d_in, const int* in_sizes, int n_in,
                              void* d_out, int out_size, void* d_ws, size_t ws_size,
                              hipStream_t stream) {
  const float* X    = (const float*)d_in[0];
  const float* Wqkv = (const float*)d_in[1];
  const float* bqkv = (const float*)d_in[2];
  const float* Wout = (const float*)d_in[3];
  const float* bout = (const float*)d_in[4];
  float* out = (float*)d_out;

  char* ws = (char*)d_ws;
  u16* Xb  = (u16*)ws;  ws += (size_t)MPAD * D_ * 2;
  u16* Wqt = (u16*)ws;  ws += (size_t)NQKV * D_ * 2;
  u16* Wot = (u16*)ws;  ws += (size_t)D_ * D_ * 2;
  u16* Qb  = (u16*)ws;  ws += (size_t)B_ * H_ * SPAD * HD_ * 2;
  u16* Kb  = (u16*)ws;  ws += (size_t)B_ * H_ * SPAD * HD_ * 2;
  u16* Vt  = (u16*)ws;  ws += (size_t)B_ * H_ * SPAD * HD_ * 2;
  u16* Ob  = (u16*)ws;  ws += (size_t)MPAD * D_ * 2;
  // total ~101 MB

  convert_kernel<<<2048, 256, 0, stream>>>(X, Wqkv, Wout, Xb, Wqt, Wot);
  // QKV: M=19200 (75 tiles of 256), N=1536 (6 tiles of 256) -> 450 blocks
  gemm_kernel<0, 4><<<450, 512, 0, stream>>>(Xb, Wqt, bqkv, 6, Qb, Kb, Vt, nullptr);
  attn_kernel<<<608, 256, 0, stream>>>(Qb, Kb, Vt, Ob);
  // OUT: M=19200, N=512 (4 tiles of 128) -> 300 blocks
  gemm_kernel<1, 2><<<300, 512, 0, stream>>>(Ob, Wot, bout, 4, nullptr, nullptr, nullptr, out);
}

// Round 4
// 182.417 us; speedup vs baseline: 1.7715x; 1.4800x over previous
//
#include <hip/hip_runtime.h>
#include <stdint.h>

#define D_    512
#define H_    2
#define HD_   256
#define B_    16
#define S_    1194
#define MTOK  19104          // B_*S_
#define MPAD  19200          // 150*128
#define SPAD  1216           // 19*64
#define NQKV  1536
#define NT_   19             // q/kv tiles of 64
#define LOG2E 1.44269504088896340736f

typedef unsigned short u16;
typedef __attribute__((ext_vector_type(8))) short bf16x8;   // 8 bf16 = 4 VGPR
typedef __attribute__((ext_vector_type(4))) float f32x4;

__device__ inline u16 f2bf(float x) {
  union { float f; unsigned u; } c; c.f = x;
  unsigned r = c.u + 0x7fffu + ((c.u >> 16) & 1u);  // RNE
  return (u16)(r >> 16);
}

// async global->LDS, 16B per lane. LDS dest is wave-uniform base (HW adds
// lane*16); global src per-lane. All call sites now use CONTIGUOUS src:
// lane l reads base + l*16 -> one instruction = 1KB sequential = 8 full lines.
__device__ inline void async_copy16(void* lds, const void* g) {
  __builtin_amdgcn_global_load_lds(
      (__attribute__((address_space(1))) void*)(g),
      (__attribute__((address_space(3))) void*)(lds),
      16, 0, 0);
}

// ---------------------------------------------------------------------------
// Fragment-major global layout for a row-major [R][512] bf16 matrix, tiled
// 128 rows x 64 cols (BK): frag f = kk*8 + mf (kk = k-half, mf = 16-row blk),
// lane l holds elems (row = mf*16 + (l&15), k = kk*32 + (l>>4)*8 + e).
// u16 addr(i,k) = ((((i>>7)*8 + (k>>6))*16 + ((k>>5)&1)*8 + ((i>>4)&7))*512
//                + (((k>>3)&3)*16 + (i&15))*8 + (k&7)
// Kernel 1 produces Xf, Wqf (= W_qkv^T frag-major), Wof (= W_out^T).
// ---------------------------------------------------------------------------
__global__ void convert_kernel(const float* __restrict__ X,
                               const float* __restrict__ Wqkv,
                               const float* __restrict__ Wout,
                               u16* __restrict__ Xf,
                               u16* __restrict__ Wqf,
                               u16* __restrict__ Wof) {
  const int NXG = MPAD * 64;          // bf16x8 groups in Xf
  const int NQG = 12 * 8 * 16 * 64;   // groups in Wqf (N=1536 -> 12 tiles)
  const int NOG = 4 * 8 * 16 * 64;    // groups in Wof (N=512  -> 4 tiles)
  const int TOT = NXG + NQG + NOG;
  int stride = gridDim.x * blockDim.x;
  for (int g = blockIdx.x * blockDim.x + threadIdx.x; g < TOT; g += stride) {
    if (g < NXG) {
      int lane = g & 63, f = (g >> 6) & 15, kt = (g >> 10) & 7, mt = g >> 13;
      int i = mt * 128 + (f & 7) * 16 + (lane & 15);
      int k = kt * 64 + (f >> 3) * 32 + (lane >> 4) * 8;
      bf16x8 o;
      if (i < MTOK) {
        f32x4 v0 = *(const f32x4*)&X[(size_t)i * 512 + k];
        f32x4 v1 = *(const f32x4*)&X[(size_t)i * 512 + k + 4];
#pragma unroll
        for (int e = 0; e < 4; ++e) { o[e] = (short)f2bf(v0[e]); o[4 + e] = (short)f2bf(v1[e]); }
      } else {
#pragma unroll
        for (int e = 0; e < 8; ++e) o[e] = 0;
      }
      *(bf16x8*)&Xf[(size_t)g * 8] = o;
    } else if (g < NXG + NQG) {
      int gg = g - NXG;
      int lane = gg & 63, f = (gg >> 6) & 15, kt = (gg >> 10) & 7, nt = gg >> 13;
      int j = nt * 128 + (f & 7) * 16 + (lane & 15);
      int k = kt * 64 + (f >> 3) * 32 + (lane >> 4) * 8;
      bf16x8 o;
#pragma unroll
      for (int e = 0; e < 8; ++e) o[e] = (short)f2bf(Wqkv[(size_t)(k + e) * NQKV + j]);
      *(bf16x8*)&Wqf[(size_t)gg * 8] = o;
    } else {
      int gg = g - NXG - NQG;
      int lane = gg & 63, f = (gg >> 6) & 15, kt = (gg >> 10) & 7, nt = gg >> 13;
      int j = nt * 128 + (f & 7) * 16 + (lane & 15);
      int k = kt * 64 + (f >> 3) * 32 + (lane >> 4) * 8;
      bf16x8 o;
#pragma unroll
      for (int e = 0; e < 8; ++e) o[e] = (short)f2bf(Wout[(size_t)(k + e) * 512 + j]);
      *(bf16x8*)&Wof[(size_t)gg * 8] = o;
    }
  }
}

// ---------------------------------------------------------------------------
// Pipelined GEMM: 128x128 tile, 4 waves, K=512 (8 steps of 64), dbuf LDS
// (64 KiB -> 2 blocks/CU), all staging contiguous 1KB/instr from frag-major
// A and B. Per K-step: issue next tile's 8 stages, ds_read + 32 MFMA, barrier.
// MODE 0: QKV epilogue -> Qb row-major, Kf/Vf frag-major for attn.
// MODE 1: f32 out + bias.
// ---------------------------------------------------------------------------
template<int MODE>
__global__ __launch_bounds__(256, 2) void gemm_kernel(
    const u16* __restrict__ Af, const u16* __restrict__ Bf,
    const float* __restrict__ bias, int nb,
    u16* __restrict__ Qb, u16* __restrict__ Kf, u16* __restrict__ Vf,
    float* __restrict__ Cout)
{
  __shared__ u16 ldsA[2][16 * 512];   // 16 frags x 1KB, double-buffered
  __shared__ u16 ldsB[2][16 * 512];

  const int t  = threadIdx.x;
  const int l  = t & 63;
  const int w  = t >> 6;               // 0..3
  const int lr = l >> 4, lc = l & 15;

  // bijective XCD-chunked swizzle (m204)
  const int nwg = gridDim.x;
  const int qq = nwg >> 3, rr8 = nwg & 7;
  const int xcd = blockIdx.x & 7, off = blockIdx.x >> 3;
  const int wgid = (xcd < rr8 ? xcd * (qq + 1) : rr8 * (qq + 1) + (xcd - rr8) * qq) + off;
  const int m0 = (wgid / nb) * 128;
  const int n0 = (wgid % nb) * 128;

  // frag-major bases: tile (m0>>7) has 8 kt-steps x 16 frags x 512 u16
  const u16* pA = Af + ((size_t)(m0 >> 7) * 128 + w) * 512 + l * 8;
  const u16* pB = Bf + ((size_t)(n0 >> 7) * 128 + w) * 512 + l * 8;

  f32x4 acc[4][4] = {};

  // prologue: stage K-step 0
#pragma unroll
  for (int c = 0; c < 4; ++c) {
    async_copy16(&ldsA[0][(c * 4 + w) * 512], pA + c * 2048);
    async_copy16(&ldsB[0][(c * 4 + w) * 512], pB + c * 2048);
  }
  __syncthreads();

  for (int kt = 0; kt < 8; ++kt) {
    const int cur = kt & 1;
    if (kt < 7) {                      // issue next step's stages FIRST
      const u16* qA = pA + (kt + 1) * 8192;
      const u16* qB = pB + (kt + 1) * 8192;
#pragma unroll
      for (int c = 0; c < 4; ++c) {
        async_copy16(&ldsA[cur ^ 1][(c * 4 + w) * 512], qA + c * 2048);
        async_copy16(&ldsB[cur ^ 1][(c * 4 + w) * 512], qB + c * 2048);
      }
    }
#pragma unroll
    for (int kk = 0; kk < 2; ++kk) {
      bf16x8 af[4], bfr[4];
#pragma unroll
      for (int m = 0; m < 4; ++m)
        af[m] = *(bf16x8*)&ldsA[cur][((kk * 8 + (w >> 1) * 4 + m) * 64 + l) * 8];
#pragma unroll
      for (int n = 0; n < 4; ++n)
        bfr[n] = *(bf16x8*)&ldsB[cur][((kk * 8 + (w & 1) * 4 + n) * 64 + l) * 8];
      __builtin_amdgcn_s_setprio(1);
#pragma unroll
      for (int m = 0; m < 4; ++m)
#pragma unroll
        for (int n = 0; n < 4; ++n)
          acc[m][n] = __builtin_amdgcn_mfma_f32_16x16x32_bf16(af[m], bfr[n], acc[m][n], 0, 0, 0);
      __builtin_amdgcn_s_setprio(0);
    }
    __syncthreads();                   // next buffer landed; cur reads done
  }

  // Epilogue. C frag: col = lane&15, row = (lane>>4)*4 + reg  [m89]
  int jv[4]; float bj[4];
#pragma unroll
  for (int n = 0; n < 4; ++n) { jv[n] = n0 + (w & 1) * 64 + n * 16 + lc; bj[n] = bias[jv[n]]; }

#pragma unroll
  for (int m = 0; m < 4; ++m) {
#pragma unroll
    for (int r = 0; r < 4; ++r) {
      int i = m0 + (w >> 1) * 64 + m * 16 + lr * 4 + r;
      if (i >= MTOK) continue;
      if (MODE == 0) {
        int b = i / S_, s = i - b * S_;
        int st = s >> 6, nfs = (s >> 4) & 3, lis = s & 15;
        int kk2 = (s >> 5) & 1, lhs = (s >> 3) & 3, es = s & 7;
#pragma unroll
        for (int n = 0; n < 4; ++n) {
          int j = jv[n];
          int which = j >> 9, h = (j >> 8) & 1, d = j & 255;
          int bh = b * H_ + h;
          u16 v = f2bf(acc[m][n][r] + bj[n]);
          if (which == 0) {
            Qb[((size_t)(bh * SPAD + s)) * HD_ + d] = v;
          } else if (which == 1) {
            // K frag-major: frag = (d>>5)*4 + nfs; lane = ((d>>3)&3)*16 + lis; e = d&7
            Kf[(((size_t)(bh * NT_ + st)) * 32 + (d >> 5) * 4 + nfs) * 512 +
               (((d >> 3) & 3) * 16 + lis) * 8 + (d & 7)] = v;
          } else {
            // V frag-major: frag = kk2*16 + (d>>4); lane = lhs*16 + (d&15); e = s&7
            Vf[(((size_t)(bh * NT_ + st)) * 32 + kk2 * 16 + (d >> 4)) * 512 +
               (lhs * 16 + (d & 15)) * 8 + es] = v;
          }
        }
      } else {
#pragma unroll
        for (int n = 0; n < 4; ++n)
          Cout[(size_t)i * D_ + jv[n]] = acc[m][n][r] + bj[n];
      }
    }
  }
}

// ---------------------------------------------------------------------------
// Kernel 3: causal flash attention. Identical compute/LDS structure to the
// passing round-2/3 kernel; only (a) K/V staging sources are now frag-major
// contiguous, (b) output goes to frag-major Obf for the out-proj GEMM.
// ---------------------------------------------------------------------------
__global__ __launch_bounds__(256) void attn_kernel(
    const u16* __restrict__ Qb, const u16* __restrict__ Kf,
    const u16* __restrict__ Vf, u16* __restrict__ Obf)
{
  __shared__ u16 ldsK[32 * 64 * 8];       // 32 KiB, slot = kb*4+nf
  __shared__ u16 ldsV[32 * 64 * 8];       // 32 KiB, slot = kk*16+vf
  __shared__ u16 ldsP[4][16 * 72];        // per-wave P, padded stride 72

  const int id   = blockIdx.x;            // 0..607
  const int xcd  = id & 7;
  const int slot = id >> 3;               // 0..75
  const int bh   = xcd + 8 * (slot / NT_);
  const int qt   = (NT_ - 1) - (slot % NT_);   // long blocks first
  const int q0 = qt * 64;
  const int t  = threadIdx.x, l = t & 63, w = t >> 6;
  const int lr = l >> 4, lc = l & 15;

  bf16x8 qf[8];
  const u16* qbase = Qb + (size_t)(bh * SPAD + q0 + w * 16 + lc) * HD_ + lr * 8;
#pragma unroll
  for (int kb = 0; kb < 8; ++kb)
    qf[kb] = *(const bf16x8*)(qbase + kb * 32);

  f32x4 oacc[16] = {};
  float mrow[4] = {-1e30f, -1e30f, -1e30f, -1e30f};
  float lsum[4] = {0.f, 0.f, 0.f, 0.f};

  for (int kt = 0; kt <= qt; ++kt) {
    const u16* kbase = Kf + (((size_t)(bh * NT_ + kt)) * 32 + w) * 512 + l * 8;
    const u16* vbase = Vf + (((size_t)(bh * NT_ + kt)) * 32 + w) * 512 + l * 8;
    __syncthreads();
#pragma unroll
    for (int c = 0; c < 8; ++c) {         // 32 K-frags + 32 V-frags, contiguous
      async_copy16(&ldsK[(c * 4 + w) * 512], kbase + c * 2048);
      async_copy16(&ldsV[(c * 4 + w) * 512], vbase + c * 2048);
    }
    __syncthreads();

    const int kv0 = kt * 64;
    f32x4 sacc[4] = {};
#pragma unroll
    for (int kb = 0; kb < 8; ++kb) {
#pragma unroll
      for (int nf = 0; nf < 4; ++nf) {
        bf16x8 kf = *(bf16x8*)&ldsK[((kb * 4 + nf) * 64 + l) * 8];
        sacc[nf] = __builtin_amdgcn_mfma_f32_16x16x32_bf16(qf[kb], kf, sacc[nf], 0, 0, 0);
      }
    }

    float sval[4][4];
    float pm[4] = {-1e30f, -1e30f, -1e30f, -1e30f};
#pragma unroll
    for (int nf = 0; nf < 4; ++nf) {
      int col = kv0 + nf * 16 + lc;
#pragma unroll
      for (int r = 0; r < 4; ++r) {
        int row = q0 + w * 16 + lr * 4 + r;
        float v = ((col <= row) && (col < S_)) ? sacc[nf][r] * 0.0625f : -1e30f;
        sval[nf][r] = v;
        pm[r] = fmaxf(pm[r], v);
      }
    }
#pragma unroll
    for (int r = 0; r < 4; ++r) {
      pm[r] = fmaxf(pm[r], __shfl_xor(pm[r], 1));
      pm[r] = fmaxf(pm[r], __shfl_xor(pm[r], 2));
      pm[r] = fmaxf(pm[r], __shfl_xor(pm[r], 4));
      pm[r] = fmaxf(pm[r], __shfl_xor(pm[r], 8));
      float mn = fmaxf(mrow[r], pm[r]);
      float sc = exp2f((mrow[r] - mn) * LOG2E);
      mrow[r] = mn;
      lsum[r] *= sc;
#pragma unroll
      for (int nf = 0; nf < 16; ++nf) oacc[nf][r] *= sc;
    }
#pragma unroll
    for (int nf = 0; nf < 4; ++nf) {
#pragma unroll
      for (int r = 0; r < 4; ++r) {
        float p = exp2f((sval[nf][r] - mrow[r]) * LOG2E);
        lsum[r] += p;
        ldsP[w][(lr * 4 + r) * 72 + nf * 16 + lc] = f2bf(p);
      }
    }
    // no barrier: P is wave-private (same-wave lgkm ordering)

#pragma unroll
    for (int kk = 0; kk < 2; ++kk) {
      bf16x8 pf = *(bf16x8*)&ldsP[w][lc * 72 + kk * 32 + lr * 8];
#pragma unroll
      for (int nf = 0; nf < 16; ++nf) {
        bf16x8 vf = *(bf16x8*)&ldsV[((kk * 16 + nf) * 64 + l) * 8];
        oacc[nf] = __builtin_amdgcn_mfma_f32_16x16x32_bf16(pf, vf, oacc[nf], 0, 0, 0);
      }
    }
  }

  float inv[4];
#pragma unroll
  for (int r = 0; r < 4; ++r) {
    float s = lsum[r];
    s += __shfl_xor(s, 1); s += __shfl_xor(s, 2);
    s += __shfl_xor(s, 4); s += __shfl_xor(s, 8);
    inv[r] = 1.0f / s;
  }
  const int b = bh >> 1, h = bh & 1;
#pragma unroll
  for (int r = 0; r < 4; ++r) {
    int q = q0 + w * 16 + lr * 4 + r;
    if (q < S_) {
      int i = b * S_ + q;
      int it = i >> 7, mf = (i >> 4) & 7, li = i & 15;
#pragma unroll
      for (int nf = 0; nf < 16; ++nf) {
        int j = h * HD_ + nf * 16 + lc;
        // frag-major A-layout for the out-proj GEMM
        size_t addr = (((size_t)(it * 8 + (j >> 6))) * 16 + ((j >> 5) & 1) * 8 + mf) * 512 +
                      (((j >> 3) & 3) * 16 + li) * 8 + (j & 7);
        Obf[addr] = f2bf(oacc[nf][r] * inv[r]);
      }
    }
  }
}

// ---------------------------------------------------------------------------
extern "C" void kernel_launch(void* const* d_in, const int* in_sizes, int n_in,
                              void* d_out, int out_size, void* d_ws, size_t ws_size,
                              hipStream_t stream) {
  const float* X    = (const float*)d_in[0];
  const float* Wqkv = (const float*)d_in[1];
  const float* bqkv = (const float*)d_in[2];
  const float* Wout = (const float*)d_in[3];
  const float* bout = (const float*)d_in[4];
  float* out = (float*)d_out;

  char* ws = (char*)d_ws;
  u16* Xf  = (u16*)ws;  ws += (size_t)MPAD * D_ * 2;
  u16* Wqf = (u16*)ws;  ws += (size_t)NQKV * D_ * 2;
  u16* Wof = (u16*)ws;  ws += (size_t)D_ * D_ * 2;
  u16* Qb  = (u16*)ws;  ws += (size_t)B_ * H_ * SPAD * HD_ * 2;
  u16* Kf  = (u16*)ws;  ws += (size_t)B_ * H_ * SPAD * HD_ * 2;
  u16* Vf  = (u16*)ws;  ws += (size_t)B_ * H_ * SPAD * HD_ * 2;
  u16* Obf = (u16*)ws;  ws += (size_t)MPAD * D_ * 2;
  // total ~101 MB

  convert_kernel<<<2048, 256, 0, stream>>>(X, Wqkv, Wout, Xf, Wqf, Wof);
  // QKV: M=19200 (150 tiles of 128), N=1536 (12 tiles of 128) -> 1800 blocks
  gemm_kernel<0><<<1800, 256, 0, stream>>>(Xf, Wqf, bqkv, 12, Qb, Kf, Vf, nullptr);
  attn_kernel<<<608, 256, 0, stream>>>(Qb, Kf, Vf, Obf);
  // OUT: M=19200, N=512 (4 tiles of 128) -> 600 blocks
  gemm_kernel<1><<<600, 256, 0, stream>>>(Obf, Wof, bout, 4, nullptr, nullptr, nullptr, out);
}